// Round 18
// baseline (253.312 us; speedup 1.0000x reference)
//
#include <hip/hip_runtime.h>

#define TLEN   500000
#define NITER  100
#define DHALF  6                  // band half-width
#define NOFF   (2*DHALF+1)        // 13 offsets
#define STRIP  20                 // edge strip width
#define EWIN   32                 // edge window
#define CT     64                 // conv threads per block (one wave)
#define CCPT   8                  // conv cols per thread
#define NCONV  ((TLEN - 2*STRIP + CT*CCPT - 1) / (CT*CCPT))   // 977
#define WROW   128                // padded weights per source-row k

// ============ K1: band weights (blocks 0-11) + edge strips (blocks 12,13) ============
// (R12/R15 kernel, measured-good & validated.)
__global__ __launch_bounds__(256) void band_and_edges(
    const float* __restrict__ xs, const float* __restrict__ ys,
    const float* __restrict__ F, const float* __restrict__ H,
    const float* __restrict__ Q, const float* __restrict__ R,
    const float* __restrict__ gam,
    float* __restrict__ wout,            // d_ws: 12*WROW floats, layout [k][d*8+i], pad 0
    float* __restrict__ out)
{
  __shared__ double dQaug[8][16];
  __shared__ double dRaug[4][8];
  __shared__ double dFtQi[64], dHtRi[32], dA1[64], dB2[64];
  __shared__ float fmats[224];
  __shared__ __align__(16) float st[2][34][8];   // ping-pong column states

  const int tid = threadIdx.x;
  const int b   = blockIdx.x;
  const int r8  = (tid >> 3) & 7;
  const int c8  = tid & 7;

  if (tid < 64) {
    dQaug[r8][c8]     = (double)Q[r8*8 + c8];
    dQaug[r8][c8 + 8] = (c8 == r8) ? 1.0 : 0.0;
  } else if (tid < 96) {
    int t = tid - 64, rr = t >> 3, cr = t & 7;
    dRaug[rr][cr] = (cr < 4) ? (double)R[rr*4 + cr] : ((cr - 4 == rr) ? 1.0 : 0.0);
  }
  __syncthreads();
  for (int col = 0; col < 8; ++col) {      // Gauss-Jordan (Q,R SPD: no pivoting)
    double piv = 1, fq = 0, p1 = 0, p2 = 0, m1 = 0, m2 = 0;
    double rpiv = 1, frr = 0, pr = 0, mr = 0;
    const bool doQ = tid < 64;
    const bool doR = (tid >= 64 && tid < 96 && col < 4);
    if (doQ) {
      piv = dQaug[col][col]; fq = dQaug[r8][col];
      p1 = dQaug[col][c8];   p2 = dQaug[col][c8 + 8];
      m1 = dQaug[r8][c8];    m2 = dQaug[r8][c8 + 8];
    }
    if (doR) {
      int t = tid - 64, rr = t >> 3, cr = t & 7;
      rpiv = dRaug[col][col]; frr = dRaug[rr][col];
      pr = dRaug[col][cr];    mr = dRaug[rr][cr];
    }
    __syncthreads();
    if (doQ) {
      dQaug[r8][c8]     = (r8 == col) ? m1 / piv : m1 - fq * (p1 / piv);
      dQaug[r8][c8 + 8] = (r8 == col) ? m2 / piv : m2 - fq * (p2 / piv);
    }
    if (doR) {
      int t = tid - 64, rr = t >> 3, cr = t & 7;
      dRaug[rr][cr] = (rr == col) ? mr / rpiv : mr - frr * (pr / rpiv);
    }
    __syncthreads();
  }
  if (tid < 64) {
    double s = 0.0;
    #pragma unroll
    for (int k = 0; k < 8; ++k) s += (double)F[k*8 + r8] * dQaug[k][c8 + 8];
    dFtQi[r8*8 + c8] = s;
    dA1[r8*8 + c8] = (c8 == 0) ? 0.0 : -dQaug[r8][c8 + 8];
  } else if (tid < 96) {
    int t = tid - 64, i = t >> 2, j = t & 3;
    double s = 0.0;
    #pragma unroll
    for (int k = 0; k < 4; ++k) s += (double)H[k*8 + i] * dRaug[k][j + 4];
    dHtRi[i*4 + j] = s;
  }
  __syncthreads();
  if (tid < 64) dB2[r8*8 + c8] = (c8 == 7) ? 0.0 : dFtQi[r8*8 + c8];
  __syncthreads();
  {
    const double g = (double)gam[0];
    if (tid < 64) {
      double sp = 0.0;
      #pragma unroll
      for (int k = 0; k < 8; ++k) sp -= dA1[r8*8 + k] * (double)F[k*8 + c8];
      double t2 = dA1[r8*8 + c8];
      #pragma unroll
      for (int k = 0; k < 8; ++k) t2 -= dB2[r8*8 + k] * (double)F[k*8 + c8];
      #pragma unroll
      for (int k = 0; k < 4; ++k) t2 -= dHtRi[r8*4 + k] * (double)H[k*8 + c8];
      fmats[       c8*8 + r8] = (float)(((r8 == c8) ? 1.0 : 0.0) + g * t2);
      fmats[ 64 +  c8*8 + r8] = (float)(g * sp);
      fmats[128 +  c8*8 + r8] = (float)(g * dB2[r8*8 + c8]);
    } else if (tid < 96) {
      int t = tid - 64, i = t >> 2, j = t & 3;
      fmats[192 + j*8 + i] = (float)(g * dHtRi[i*4 + j]);
    }
  }
  __syncthreads();

  const int i = tid & 7;
  const int g = tid >> 3;
  float cmr[8], pmr[8], fur[7];
  #pragma unroll
  for (int k = 0; k < 8; ++k) {
    cmr[k] = fmats[       k*8 + i];
    pmr[k] = fmats[ 64 +  k*8 + i];
    if (k < 7) fur[k] = fmats[128 + k*8 + i];
  }
  float* const stf = (float*)st;
  const int BUF = 34*8;

  if (b < 12) {
    const int c = b;
    const bool act = tid < NOFF*8;
    const int s = g + 1;
    for (int idx = tid; idx < 2*BUF; idx += 256) stf[idx] = 0.0f;
    __syncthreads();
    if (act && c < 8 && s == DHALF + 1 && i == c) st[0][s][i] = 1.0f;
    const float seed = (act && c >= 8 && s == DHALF + 1) ? fmats[192 + (c - 8)*8 + i] : 0.0f;
    __syncthreads();
    int p = 0;
    float last = 0.0f;
    #pragma unroll 1
    for (int it = 0; it < NITER; ++it) {
      if (act) {
        const float* sp_ = stf + p*BUF;
        const float4 o0 = *(const float4*)(sp_ + s*8);
        const float4 o1 = *(const float4*)(sp_ + s*8 + 4);
        const float4 u0 = *(const float4*)(sp_ + (s + 1)*8);
        const float4 u1 = *(const float4*)(sp_ + (s + 1)*8 + 4);
        const float4 d0 = *(const float4*)(sp_ + (s - 1)*8);
        const float4 d1 = *(const float4*)(sp_ + (s - 1)*8 + 4);
        float a0 = seed, a1 = 0.0f, a2 = 0.0f;
        a0 = fmaf(cmr[0], o0.x, a0); a0 = fmaf(cmr[1], o0.y, a0);
        a0 = fmaf(cmr[2], o0.z, a0); a0 = fmaf(cmr[3], o0.w, a0);
        a0 = fmaf(cmr[4], o1.x, a0); a0 = fmaf(cmr[5], o1.y, a0);
        a0 = fmaf(cmr[6], o1.z, a0); a0 = fmaf(cmr[7], o1.w, a0);
        a1 = fmaf(pmr[0], u0.x, a1); a1 = fmaf(pmr[1], u0.y, a1);
        a1 = fmaf(pmr[2], u0.z, a1); a1 = fmaf(pmr[3], u0.w, a1);
        a1 = fmaf(pmr[4], u1.x, a1); a1 = fmaf(pmr[5], u1.y, a1);
        a1 = fmaf(pmr[6], u1.z, a1); a1 = fmaf(pmr[7], u1.w, a1);
        a2 = fmaf(fur[0], d0.x, a2); a2 = fmaf(fur[1], d0.y, a2);
        a2 = fmaf(fur[2], d0.z, a2); a2 = fmaf(fur[3], d0.w, a2);
        a2 = fmaf(fur[4], d1.x, a2); a2 = fmaf(fur[5], d1.y, a2);
        a2 = fmaf(fur[6], d1.z, a2);
        last = a0 + a1 + a2;
        stf[(p^1)*BUF + s*8 + i] = last;
      }
      __syncthreads();
      p ^= 1;
    }
    if (act) wout[c*WROW + (s - 1)*8 + i] = last;
    if (tid >= NOFF*8 && tid < WROW) wout[c*WROW + tid] = 0.0f;
    return;
  }

  const bool left = (b == 12);
  const int col  = g;
  const int gcol = left ? col : (TLEN - EWIN + col);
  const int sL = (col > 0) ? col - 1 : 0;
  const int sR = (col < EWIN - 1) ? col + 1 : EWIN - 1;
  const float xv = xs[i*TLEN + gcol];
  float gyv;
  {
    gyv = fmats[192 +      i] * ys[0*TLEN + gcol];
    gyv = fmaf(fmats[192 +  8 + i], ys[1*TLEN + gcol], gyv);
    gyv = fmaf(fmats[192 + 16 + i], ys[2*TLEN + gcol], gyv);
    gyv = fmaf(fmats[192 + 24 + i], ys[3*TLEN + gcol], gyv);
  }
  st[0][col][i] = xv;
  __syncthreads();
  int p = 0;
  float last = xv;
  #pragma unroll 1
  for (int it = 0; it < NITER; ++it) {
    const float* sp_ = stf + p*BUF;
    const float4 o0 = *(const float4*)(sp_ + col*8);
    const float4 o1 = *(const float4*)(sp_ + col*8 + 4);
    const float4 l0 = *(const float4*)(sp_ + sL*8);
    const float4 l1 = *(const float4*)(sp_ + sL*8 + 4);
    const float4 q0 = *(const float4*)(sp_ + sR*8);
    const float4 q1 = *(const float4*)(sp_ + sR*8 + 4);
    float a0 = gyv, a1 = 0.0f, a2 = 0.0f;
    a0 = fmaf(cmr[0], o0.x, a0); a0 = fmaf(cmr[1], o0.y, a0);
    a0 = fmaf(cmr[2], o0.z, a0); a0 = fmaf(cmr[3], o0.w, a0);
    a0 = fmaf(cmr[4], o1.x, a0); a0 = fmaf(cmr[5], o1.y, a0);
    a0 = fmaf(cmr[6], o1.z, a0); a0 = fmaf(cmr[7], o1.w, a0);
    a1 = fmaf(pmr[0], l0.x, a1); a1 = fmaf(pmr[1], l0.y, a1);
    a1 = fmaf(pmr[2], l0.z, a1); a1 = fmaf(pmr[3], l0.w, a1);
    a1 = fmaf(pmr[4], l1.x, a1); a1 = fmaf(pmr[5], l1.y, a1);
    a1 = fmaf(pmr[6], l1.z, a1); a1 = fmaf(pmr[7], l1.w, a1);
    a2 = fmaf(fur[0], q0.x, a2); a2 = fmaf(fur[1], q0.y, a2);
    a2 = fmaf(fur[2], q0.z, a2); a2 = fmaf(fur[3], q0.w, a2);
    a2 = fmaf(fur[4], q1.x, a2); a2 = fmaf(fur[5], q1.y, a2);
    a2 = fmaf(fur[6], q1.z, a2);
    last = a0 + a1 + a2;
    stf[(p^1)*BUF + col*8 + i] = last;
    __syncthreads();
    p ^= 1;
  }
  if (left ? (col < STRIP) : (col >= EWIN - STRIP)) out[i*TLEN + gcol] = last;
}

// ============ K2: conv — CCPT=8, LDS-broadcast weights, 64 acc chains ============
// One thread owns 8 cols x 8 rows x all 12 k. Per k: 6 float4 z-loads + 26
// uniform-address LDS weight reads feed 832 FMAs (ratio ~26:1) — weight/z
// latency hides under the FMA stream via in-thread ILP (64 indep. chains).
__global__ __launch_bounds__(CT, 1) void kgm_conv(
    const float* __restrict__ xs, const float* __restrict__ ys,
    const float* __restrict__ wq, float* __restrict__ out)
{
  __shared__ __align__(16) float wl[12 * WROW];   // 6 KB
  const int lane = threadIdx.x;
  #pragma unroll
  for (int t = 0; t < 6; ++t) {                   // 384 float4 chunks / 64 lanes
    const int idx = lane + t*64;
    *(float4*)(wl + 4*idx) = *(const float4*)(wq + 4*idx);
  }
  __syncthreads();

  int c0 = STRIP + (blockIdx.x * CT + lane) * CCPT;
  const bool str = (c0 < TLEN - STRIP);           // 8-col groups all-or-nothing
  if (c0 > TLEN - STRIP - CCPT) c0 = TLEN - STRIP - CCPT;

  float acc[8][8];
  #pragma unroll
  for (int i = 0; i < 8; ++i)
    #pragma unroll
    for (int j = 0; j < 8; ++j) acc[i][j] = 0.0f;

  #pragma unroll
  for (int k = 0; k < 12; ++k) {
    const float* src = ((k < 8) ? (xs + k*TLEN) : (ys + (k-8)*TLEN)) + c0;
    float z[24];                                  // cols [c0-8, c0+16), 16B-aligned
    #pragma unroll
    for (int t = 0; t < 6; ++t) {
      float4 v = *(const float4*)(src - 8 + 4*t);
      z[4*t] = v.x; z[4*t+1] = v.y; z[4*t+2] = v.z; z[4*t+3] = v.w;
    }
    const float* wk = wl + k*WROW;
    #pragma unroll
    for (int d = 0; d < NOFF; ++d) {
      const float4 wa = *(const float4*)(wk + d*8);       // uniform: broadcast
      const float4 wb = *(const float4*)(wk + d*8 + 4);
      #pragma unroll
      for (int j = 0; j < 8; ++j) {                       // out col c0+j <- in c0+j+d-6
        const float zz = z[j + d + 2];
        acc[0][j] = fmaf(wa.x, zz, acc[0][j]);
        acc[1][j] = fmaf(wa.y, zz, acc[1][j]);
        acc[2][j] = fmaf(wa.z, zz, acc[2][j]);
        acc[3][j] = fmaf(wa.w, zz, acc[3][j]);
        acc[4][j] = fmaf(wb.x, zz, acc[4][j]);
        acc[5][j] = fmaf(wb.y, zz, acc[5][j]);
        acc[6][j] = fmaf(wb.z, zz, acc[6][j]);
        acc[7][j] = fmaf(wb.w, zz, acc[7][j]);
      }
    }
  }

  if (str) {
    #pragma unroll
    for (int i = 0; i < 8; ++i) {
      float4 o0, o1;
      o0.x = acc[i][0]; o0.y = acc[i][1]; o0.z = acc[i][2]; o0.w = acc[i][3];
      o1.x = acc[i][4]; o1.y = acc[i][5]; o1.z = acc[i][6]; o1.w = acc[i][7];
      *(float4*)(out + i*TLEN + c0)     = o0;
      *(float4*)(out + i*TLEN + c0 + 4) = o1;
    }
  }
}

extern "C" void kernel_launch(void* const* d_in, const int* in_sizes, int n_in,
                              void* d_out, int out_size, void* d_ws, size_t ws_size,
                              hipStream_t stream)
{
  (void)in_sizes; (void)n_in; (void)out_size; (void)ws_size;
  const float* xs = (const float*)d_in[0];
  const float* ys = (const float*)d_in[1];
  const float* F  = (const float*)d_in[2];
  const float* H  = (const float*)d_in[3];
  const float* Q  = (const float*)d_in[4];
  const float* R  = (const float*)d_in[5];
  const float* ga = (const float*)d_in[6];
  float* ws  = (float*)d_ws;     // [0, 12*WROW): band weights [k][d*8+i], pad 0
  float* out = (float*)d_out;
  band_and_edges<<<14, 256, 0, stream>>>(xs, ys, F, H, Q, R, ga, ws, out);
  kgm_conv<<<NCONV, CT, 0, stream>>>(xs, ys, ws, out);
}

// Round 19
// 68.883 us; speedup vs baseline: 3.6774x; 3.6774x over previous
//
#include <hip/hip_runtime.h>

#define TLEN   500000
#define NITER  100
#define DHALF  6                  // band half-width
#define NOFF   (2*DHALF+1)        // 13 offsets
#define STRIP  20                 // edge strip width
#define EWIN   32                 // edge window
#define CT     64                 // conv threads per block (one wave)
#define CCPT   8                  // conv cols per thread
#define NCONV  ((TLEN - 2*STRIP + CT*CCPT - 1) / (CT*CCPT))   // 977
#define WROW   128                // padded weights per source-row k

// ============ K1: band weights (blocks 0-11) + edge strips (blocks 12,13) ============
// (R12/R15 kernel, measured-good & validated.)
__global__ __launch_bounds__(256) void band_and_edges(
    const float* __restrict__ xs, const float* __restrict__ ys,
    const float* __restrict__ F, const float* __restrict__ H,
    const float* __restrict__ Q, const float* __restrict__ R,
    const float* __restrict__ gam,
    float* __restrict__ wout,            // d_ws: 12*WROW floats, layout [k][d*8+i], pad 0
    float* __restrict__ out)
{
  __shared__ double dQaug[8][16];
  __shared__ double dRaug[4][8];
  __shared__ double dFtQi[64], dHtRi[32], dA1[64], dB2[64];
  __shared__ float fmats[224];
  __shared__ __align__(16) float st[2][34][8];   // ping-pong column states

  const int tid = threadIdx.x;
  const int b   = blockIdx.x;
  const int r8  = (tid >> 3) & 7;
  const int c8  = tid & 7;

  if (tid < 64) {
    dQaug[r8][c8]     = (double)Q[r8*8 + c8];
    dQaug[r8][c8 + 8] = (c8 == r8) ? 1.0 : 0.0;
  } else if (tid < 96) {
    int t = tid - 64, rr = t >> 3, cr = t & 7;
    dRaug[rr][cr] = (cr < 4) ? (double)R[rr*4 + cr] : ((cr - 4 == rr) ? 1.0 : 0.0);
  }
  __syncthreads();
  for (int col = 0; col < 8; ++col) {      // Gauss-Jordan (Q,R SPD: no pivoting)
    double piv = 1, fq = 0, p1 = 0, p2 = 0, m1 = 0, m2 = 0;
    double rpiv = 1, frr = 0, pr = 0, mr = 0;
    const bool doQ = tid < 64;
    const bool doR = (tid >= 64 && tid < 96 && col < 4);
    if (doQ) {
      piv = dQaug[col][col]; fq = dQaug[r8][col];
      p1 = dQaug[col][c8];   p2 = dQaug[col][c8 + 8];
      m1 = dQaug[r8][c8];    m2 = dQaug[r8][c8 + 8];
    }
    if (doR) {
      int t = tid - 64, rr = t >> 3, cr = t & 7;
      rpiv = dRaug[col][col]; frr = dRaug[rr][col];
      pr = dRaug[col][cr];    mr = dRaug[rr][cr];
    }
    __syncthreads();
    if (doQ) {
      dQaug[r8][c8]     = (r8 == col) ? m1 / piv : m1 - fq * (p1 / piv);
      dQaug[r8][c8 + 8] = (r8 == col) ? m2 / piv : m2 - fq * (p2 / piv);
    }
    if (doR) {
      int t = tid - 64, rr = t >> 3, cr = t & 7;
      dRaug[rr][cr] = (rr == col) ? mr / rpiv : mr - frr * (pr / rpiv);
    }
    __syncthreads();
  }
  if (tid < 64) {
    double s = 0.0;
    #pragma unroll
    for (int k = 0; k < 8; ++k) s += (double)F[k*8 + r8] * dQaug[k][c8 + 8];
    dFtQi[r8*8 + c8] = s;
    dA1[r8*8 + c8] = (c8 == 0) ? 0.0 : -dQaug[r8][c8 + 8];
  } else if (tid < 96) {
    int t = tid - 64, i = t >> 2, j = t & 3;
    double s = 0.0;
    #pragma unroll
    for (int k = 0; k < 4; ++k) s += (double)H[k*8 + i] * dRaug[k][j + 4];
    dHtRi[i*4 + j] = s;
  }
  __syncthreads();
  if (tid < 64) dB2[r8*8 + c8] = (c8 == 7) ? 0.0 : dFtQi[r8*8 + c8];
  __syncthreads();
  {
    const double g = (double)gam[0];
    if (tid < 64) {
      double sp = 0.0;
      #pragma unroll
      for (int k = 0; k < 8; ++k) sp -= dA1[r8*8 + k] * (double)F[k*8 + c8];
      double t2 = dA1[r8*8 + c8];
      #pragma unroll
      for (int k = 0; k < 8; ++k) t2 -= dB2[r8*8 + k] * (double)F[k*8 + c8];
      #pragma unroll
      for (int k = 0; k < 4; ++k) t2 -= dHtRi[r8*4 + k] * (double)H[k*8 + c8];
      fmats[       c8*8 + r8] = (float)(((r8 == c8) ? 1.0 : 0.0) + g * t2);
      fmats[ 64 +  c8*8 + r8] = (float)(g * sp);
      fmats[128 +  c8*8 + r8] = (float)(g * dB2[r8*8 + c8]);
    } else if (tid < 96) {
      int t = tid - 64, i = t >> 2, j = t & 3;
      fmats[192 + j*8 + i] = (float)(g * dHtRi[i*4 + j]);
    }
  }
  __syncthreads();

  const int i = tid & 7;
  const int g = tid >> 3;
  float cmr[8], pmr[8], fur[7];
  #pragma unroll
  for (int k = 0; k < 8; ++k) {
    cmr[k] = fmats[       k*8 + i];
    pmr[k] = fmats[ 64 +  k*8 + i];
    if (k < 7) fur[k] = fmats[128 + k*8 + i];
  }
  float* const stf = (float*)st;
  const int BUF = 34*8;

  if (b < 12) {
    const int c = b;
    const bool act = tid < NOFF*8;
    const int s = g + 1;
    for (int idx = tid; idx < 2*BUF; idx += 256) stf[idx] = 0.0f;
    __syncthreads();
    if (act && c < 8 && s == DHALF + 1 && i == c) st[0][s][i] = 1.0f;
    const float seed = (act && c >= 8 && s == DHALF + 1) ? fmats[192 + (c - 8)*8 + i] : 0.0f;
    __syncthreads();
    int p = 0;
    float last = 0.0f;
    #pragma unroll 1
    for (int it = 0; it < NITER; ++it) {
      if (act) {
        const float* sp_ = stf + p*BUF;
        const float4 o0 = *(const float4*)(sp_ + s*8);
        const float4 o1 = *(const float4*)(sp_ + s*8 + 4);
        const float4 u0 = *(const float4*)(sp_ + (s + 1)*8);
        const float4 u1 = *(const float4*)(sp_ + (s + 1)*8 + 4);
        const float4 d0 = *(const float4*)(sp_ + (s - 1)*8);
        const float4 d1 = *(const float4*)(sp_ + (s - 1)*8 + 4);
        float a0 = seed, a1 = 0.0f, a2 = 0.0f;
        a0 = fmaf(cmr[0], o0.x, a0); a0 = fmaf(cmr[1], o0.y, a0);
        a0 = fmaf(cmr[2], o0.z, a0); a0 = fmaf(cmr[3], o0.w, a0);
        a0 = fmaf(cmr[4], o1.x, a0); a0 = fmaf(cmr[5], o1.y, a0);
        a0 = fmaf(cmr[6], o1.z, a0); a0 = fmaf(cmr[7], o1.w, a0);
        a1 = fmaf(pmr[0], u0.x, a1); a1 = fmaf(pmr[1], u0.y, a1);
        a1 = fmaf(pmr[2], u0.z, a1); a1 = fmaf(pmr[3], u0.w, a1);
        a1 = fmaf(pmr[4], u1.x, a1); a1 = fmaf(pmr[5], u1.y, a1);
        a1 = fmaf(pmr[6], u1.z, a1); a1 = fmaf(pmr[7], u1.w, a1);
        a2 = fmaf(fur[0], d0.x, a2); a2 = fmaf(fur[1], d0.y, a2);
        a2 = fmaf(fur[2], d0.z, a2); a2 = fmaf(fur[3], d0.w, a2);
        a2 = fmaf(fur[4], d1.x, a2); a2 = fmaf(fur[5], d1.y, a2);
        a2 = fmaf(fur[6], d1.z, a2);
        last = a0 + a1 + a2;
        stf[(p^1)*BUF + s*8 + i] = last;
      }
      __syncthreads();
      p ^= 1;
    }
    if (act) wout[c*WROW + (s - 1)*8 + i] = last;
    if (tid >= NOFF*8 && tid < WROW) wout[c*WROW + tid] = 0.0f;
    return;
  }

  const bool left = (b == 12);
  const int col  = g;
  const int gcol = left ? col : (TLEN - EWIN + col);
  const int sL = (col > 0) ? col - 1 : 0;
  const int sR = (col < EWIN - 1) ? col + 1 : EWIN - 1;
  const float xv = xs[i*TLEN + gcol];
  float gyv;
  {
    gyv = fmats[192 +      i] * ys[0*TLEN + gcol];
    gyv = fmaf(fmats[192 +  8 + i], ys[1*TLEN + gcol], gyv);
    gyv = fmaf(fmats[192 + 16 + i], ys[2*TLEN + gcol], gyv);
    gyv = fmaf(fmats[192 + 24 + i], ys[3*TLEN + gcol], gyv);
  }
  st[0][col][i] = xv;
  __syncthreads();
  int p = 0;
  float last = xv;
  #pragma unroll 1
  for (int it = 0; it < NITER; ++it) {
    const float* sp_ = stf + p*BUF;
    const float4 o0 = *(const float4*)(sp_ + col*8);
    const float4 o1 = *(const float4*)(sp_ + col*8 + 4);
    const float4 l0 = *(const float4*)(sp_ + sL*8);
    const float4 l1 = *(const float4*)(sp_ + sL*8 + 4);
    const float4 q0 = *(const float4*)(sp_ + sR*8);
    const float4 q1 = *(const float4*)(sp_ + sR*8 + 4);
    float a0 = gyv, a1 = 0.0f, a2 = 0.0f;
    a0 = fmaf(cmr[0], o0.x, a0); a0 = fmaf(cmr[1], o0.y, a0);
    a0 = fmaf(cmr[2], o0.z, a0); a0 = fmaf(cmr[3], o0.w, a0);
    a0 = fmaf(cmr[4], o1.x, a0); a0 = fmaf(cmr[5], o1.y, a0);
    a0 = fmaf(cmr[6], o1.z, a0); a0 = fmaf(cmr[7], o1.w, a0);
    a1 = fmaf(pmr[0], l0.x, a1); a1 = fmaf(pmr[1], l0.y, a1);
    a1 = fmaf(pmr[2], l0.z, a1); a1 = fmaf(pmr[3], l0.w, a1);
    a1 = fmaf(pmr[4], l1.x, a1); a1 = fmaf(pmr[5], l1.y, a1);
    a1 = fmaf(pmr[6], l1.z, a1); a1 = fmaf(pmr[7], l1.w, a1);
    a2 = fmaf(fur[0], q0.x, a2); a2 = fmaf(fur[1], q0.y, a2);
    a2 = fmaf(fur[2], q0.z, a2); a2 = fmaf(fur[3], q0.w, a2);
    a2 = fmaf(fur[4], q1.x, a2); a2 = fmaf(fur[5], q1.y, a2);
    a2 = fmaf(fur[6], q1.z, a2);
    last = a0 + a1 + a2;
    stf[(p^1)*BUF + col*8 + i] = last;
    __syncthreads();
    p ^= 1;
  }
  if (left ? (col < STRIP) : (col >= EWIN - STRIP)) out[i*TLEN + gcol] = last;
}

// ============ K2: conv — CCPT=8, LDS weights, ROLLED k-loop, VGPR-capped ============
// One thread owns 8 cols x 8 rows x all 12 k. k-loop is NOT unrolled: live set
// stays at 64 acc + 24 z + misc (~105 VGPR); __launch_bounds__(64,4) caps the
// allocator at 128. Per iter: 6 float4 z-loads + 26 uniform LDS reads + 832 FMA.
__global__ __launch_bounds__(CT, 4) void kgm_conv(
    const float* __restrict__ xs, const float* __restrict__ ys,
    const float* __restrict__ wq, float* __restrict__ out)
{
  __shared__ __align__(16) float wl[12 * WROW];   // 6 KB
  const int lane = threadIdx.x;
  #pragma unroll
  for (int t = 0; t < 6; ++t) {                   // 384 float4 chunks / 64 lanes
    const int idx = lane + t*64;
    *(float4*)(wl + 4*idx) = *(const float4*)(wq + 4*idx);
  }
  __syncthreads();

  int c0 = STRIP + (blockIdx.x * CT + lane) * CCPT;
  const bool str = (c0 < TLEN - STRIP);           // 8-col groups all-or-nothing
  if (c0 > TLEN - STRIP - CCPT) c0 = TLEN - STRIP - CCPT;

  float acc[8][8];
  #pragma unroll
  for (int i = 0; i < 8; ++i)
    #pragma unroll
    for (int j = 0; j < 8; ++j) acc[i][j] = 0.0f;

  #pragma unroll 1
  for (int k = 0; k < 12; ++k) {
    const float* src = ((k < 8) ? (xs + k*TLEN) : (ys + (k-8)*TLEN)) + c0;
    float z[24];                                  // cols [c0-8, c0+16), 16B-aligned
    #pragma unroll
    for (int t = 0; t < 6; ++t) {
      float4 v = *(const float4*)(src - 8 + 4*t);
      z[4*t] = v.x; z[4*t+1] = v.y; z[4*t+2] = v.z; z[4*t+3] = v.w;
    }
    const float* wk = wl + k*WROW;
    #pragma unroll
    for (int d = 0; d < NOFF; ++d) {
      const float4 wa = *(const float4*)(wk + d*8);       // uniform: broadcast
      const float4 wb = *(const float4*)(wk + d*8 + 4);
      #pragma unroll
      for (int j = 0; j < 8; ++j) {                       // out col c0+j <- in c0+j+d-6
        const float zz = z[j + d + 2];
        acc[0][j] = fmaf(wa.x, zz, acc[0][j]);
        acc[1][j] = fmaf(wa.y, zz, acc[1][j]);
        acc[2][j] = fmaf(wa.z, zz, acc[2][j]);
        acc[3][j] = fmaf(wa.w, zz, acc[3][j]);
        acc[4][j] = fmaf(wb.x, zz, acc[4][j]);
        acc[5][j] = fmaf(wb.y, zz, acc[5][j]);
        acc[6][j] = fmaf(wb.z, zz, acc[6][j]);
        acc[7][j] = fmaf(wb.w, zz, acc[7][j]);
      }
    }
  }

  if (str) {
    #pragma unroll
    for (int i = 0; i < 8; ++i) {
      float4 o0, o1;
      o0.x = acc[i][0]; o0.y = acc[i][1]; o0.z = acc[i][2]; o0.w = acc[i][3];
      o1.x = acc[i][4]; o1.y = acc[i][5]; o1.z = acc[i][6]; o1.w = acc[i][7];
      *(float4*)(out + i*TLEN + c0)     = o0;
      *(float4*)(out + i*TLEN + c0 + 4) = o1;
    }
  }
}

extern "C" void kernel_launch(void* const* d_in, const int* in_sizes, int n_in,
                              void* d_out, int out_size, void* d_ws, size_t ws_size,
                              hipStream_t stream)
{
  (void)in_sizes; (void)n_in; (void)out_size; (void)ws_size;
  const float* xs = (const float*)d_in[0];
  const float* ys = (const float*)d_in[1];
  const float* F  = (const float*)d_in[2];
  const float* H  = (const float*)d_in[3];
  const float* Q  = (const float*)d_in[4];
  const float* R  = (const float*)d_in[5];
  const float* ga = (const float*)d_in[6];
  float* ws  = (float*)d_ws;     // [0, 12*WROW): band weights [k][d*8+i], pad 0
  float* out = (float*)d_out;
  band_and_edges<<<14, 256, 0, stream>>>(xs, ys, F, H, Q, R, ga, ws, out);
  kgm_conv<<<NCONV, CT, 0, stream>>>(xs, ys, ws, out);
}

// Round 20
// 43.450 us; speedup vs baseline: 5.8300x; 1.5853x over previous
//
#include <hip/hip_runtime.h>

#define TLEN   500000
#define NITER2 50                 // iterations of the SQUARED operator (=100 base steps)
#define DHALF  6                  // band half-width
#define NOFF   (2*DHALF+1)        // 13 offsets
#define STRIP  20                 // edge strip width
#define EWIN   32                 // edge window
#define CT     256                // threads per block
#define CCPT   4                  // conv cols per thread
#define NCONV  (((TLEN - 2*STRIP)/CCPT + CT - 1) / CT)   // 489
#define WROW   128                // padded weights per source-row k
#define FMOFF  (12*WROW)          // fmats exported at ws[1536..1760)
#define NSLOT  17                 // band slots: active 2..14, 2 guards each side
#define CTR    8                  // center slot

// ============ K1: band weights via squared-operator recurrence (12 blocks) ============
// (R13 kernel, correctness-validated: 50 iterations of S^2 on independent columns.)
__global__ __launch_bounds__(256) void band_weights(
    const float* __restrict__ F, const float* __restrict__ H,
    const float* __restrict__ Q, const float* __restrict__ R,
    const float* __restrict__ gam, float* __restrict__ ws)
{
  __shared__ double dQaug[8][16];
  __shared__ double dRaug[4][8];
  __shared__ double dFtQi[64], dHtRi[32], dA1[64], dB2[64];
  __shared__ float fmats[224];
  __shared__ float t2[5][64];          // S2 blocks, transposed [f][j*8+i]
  __shared__ float v2[3][32];          // composed y-seed mats for slots 7,8,9
  __shared__ __align__(16) float st[2][NSLOT][8];

  const int tid = threadIdx.x;
  const int r8  = (tid >> 3) & 7;
  const int c8  = tid & 7;

  // ---------- double-precision operator construction ----------
  if (tid < 64) {
    dQaug[r8][c8]     = (double)Q[r8*8 + c8];
    dQaug[r8][c8 + 8] = (c8 == r8) ? 1.0 : 0.0;
  } else if (tid < 96) {
    int t = tid - 64, rr = t >> 3, cr = t & 7;
    dRaug[rr][cr] = (cr < 4) ? (double)R[rr*4 + cr] : ((cr - 4 == rr) ? 1.0 : 0.0);
  }
  __syncthreads();
  for (int col = 0; col < 8; ++col) {
    double piv = 1, fq = 0, p1 = 0, p2 = 0, m1 = 0, m2 = 0;
    double rpiv = 1, frr = 0, pr = 0, mr = 0;
    const bool doQ = tid < 64;
    const bool doR = (tid >= 64 && tid < 96 && col < 4);
    if (doQ) {
      piv = dQaug[col][col]; fq = dQaug[r8][col];
      p1 = dQaug[col][c8];   p2 = dQaug[col][c8 + 8];
      m1 = dQaug[r8][c8];    m2 = dQaug[r8][c8 + 8];
    }
    if (doR) {
      int t = tid - 64, rr = t >> 3, cr = t & 7;
      rpiv = dRaug[col][col]; frr = dRaug[rr][col];
      pr = dRaug[col][cr];    mr = dRaug[rr][cr];
    }
    __syncthreads();
    if (doQ) {
      dQaug[r8][c8]     = (r8 == col) ? m1 / piv : m1 - fq * (p1 / piv);
      dQaug[r8][c8 + 8] = (r8 == col) ? m2 / piv : m2 - fq * (p2 / piv);
    }
    if (doR) {
      int t = tid - 64, rr = t >> 3, cr = t & 7;
      dRaug[rr][cr] = (rr == col) ? mr / rpiv : mr - frr * (pr / rpiv);
    }
    __syncthreads();
  }
  if (tid < 64) {
    double s = 0.0;
    #pragma unroll
    for (int k = 0; k < 8; ++k) s += (double)F[k*8 + r8] * dQaug[k][c8 + 8];
    dFtQi[r8*8 + c8] = s;
    dA1[r8*8 + c8] = (c8 == 0) ? 0.0 : -dQaug[r8][c8 + 8];
  } else if (tid < 96) {
    int t = tid - 64, i = t >> 2, j = t & 3;
    double s = 0.0;
    #pragma unroll
    for (int k = 0; k < 4; ++k) s += (double)H[k*8 + i] * dRaug[k][j + 4];
    dHtRi[i*4 + j] = s;
  }
  __syncthreads();
  if (tid < 64) dB2[r8*8 + c8] = (c8 == 7) ? 0.0 : dFtQi[r8*8 + c8];
  __syncthreads();
  {
    const double g = (double)gam[0];
    if (tid < 64) {
      double sp = 0.0;
      #pragma unroll
      for (int k = 0; k < 8; ++k) sp -= dA1[r8*8 + k] * (double)F[k*8 + c8];
      double t2d = dA1[r8*8 + c8];
      #pragma unroll
      for (int k = 0; k < 8; ++k) t2d -= dB2[r8*8 + k] * (double)F[k*8 + c8];
      #pragma unroll
      for (int k = 0; k < 4; ++k) t2d -= dHtRi[r8*4 + k] * (double)H[k*8 + c8];
      fmats[       c8*8 + r8] = (float)(((r8 == c8) ? 1.0 : 0.0) + g * t2d);
      fmats[ 64 +  c8*8 + r8] = (float)(g * sp);
      fmats[128 +  c8*8 + r8] = (float)(g * dB2[r8*8 + c8]);
    } else if (tid < 96) {
      int t = tid - 64, i = t >> 2, j = t & 3;
      fmats[192 + j*8 + i] = (float)(g * dHtRi[i*4 + j]);
    }
  }
  __syncthreads();

  // ---------- build S2 (squared slot-shift operator) and composed y-seed ----------
  if (tid < 64) {
    const int i = tid & 7, j = tid >> 3;
    float sm2=0, sm1=0, s0=0, sp1=0, sp2=0;
    #pragma unroll
    for (int k = 0; k < 8; ++k) {
      const float cik = fmats[       k*8 + i], pik = fmats[ 64 + k*8 + i], fik = fmats[128 + k*8 + i];
      const float ckj = fmats[       j*8 + k], pkj = fmats[ 64 + j*8 + k], fkj = fmats[128 + j*8 + k];
      sm2 = fmaf(fik, fkj, sm2);
      sm1 = fmaf(fik, ckj, fmaf(cik, fkj, sm1));
      s0  = fmaf(cik, ckj, fmaf(fik, pkj, fmaf(pik, fkj, s0)));
      sp1 = fmaf(cik, pkj, fmaf(pik, ckj, sp1));
      sp2 = fmaf(pik, pkj, sp2);
    }
    t2[0][j*8+i]=sm2; t2[1][j*8+i]=sm1; t2[2][j*8+i]=s0; t2[3][j*8+i]=sp1; t2[4][j*8+i]=sp2;
  } else if (tid < 96) {
    const int t = tid - 64, i = t >> 2, j = t & 3;
    float a = 0, b = 0, c2 = 0;
    #pragma unroll
    for (int k = 0; k < 8; ++k) {
      const float gkj = fmats[192 + j*8 + k];
      a  = fmaf(fmats[ 64 + k*8 + i], gkj, a);    // P*G   -> slot 7
      b  = fmaf(fmats[       k*8 + i], gkj, b);   // Cm*G
      c2 = fmaf(fmats[128 + k*8 + i], gkj, c2);   // Fu*G  -> slot 9
    }
    v2[0][i*4+j] = a;
    v2[1][i*4+j] = b + fmats[192 + j*8 + i];      // (Cm+I)G -> slot 8
    v2[2][i*4+j] = c2;
  }
  for (int idx = tid; idx < 2*NSLOT*8; idx += 256) ((float*)st)[idx] = 0.0f;
  __syncthreads();

  const int c = blockIdx.x;            // source column 0..11 (8..11 = y cols)
  const int i = tid & 7;
  const int sa = tid >> 3;             // 0..12 active
  const bool act = tid < NOFF*8;
  const int s = sa + 2;                // slot 2..14
  if (act && c < 8 && s == CTR && i == c) st[0][CTR][i] = 1.0f;   // W_0 = I
  float seed = 0.0f;
  if (act && c >= 8) {
    const int j = c - 8;
    if (s == CTR-1) seed = v2[0][i*4 + j];
    else if (s == CTR)   seed = v2[1][i*4 + j];
    else if (s == CTR+1) seed = v2[2][i*4 + j];
  }
  float w5[5][8];
  if (act) {
    #pragma unroll
    for (int e = 0; e < 5; ++e)
      #pragma unroll
      for (int k = 0; k < 8; ++k) w5[e][k] = t2[e][k*8 + i];
  }
  __syncthreads();

  int p = 0;
  float last = 0.0f;
  #pragma unroll 1
  for (int it = 0; it < NITER2; ++it) {
    if (act) {
      float acc = seed;
      #pragma unroll
      for (int e = 0; e < 5; ++e) {
        const float4 q0 = *(const float4*)(&st[p][s - 2 + e][0]);
        const float4 q1 = *(const float4*)(&st[p][s - 2 + e][4]);
        acc = fmaf(w5[e][0], q0.x, acc); acc = fmaf(w5[e][1], q0.y, acc);
        acc = fmaf(w5[e][2], q0.z, acc); acc = fmaf(w5[e][3], q0.w, acc);
        acc = fmaf(w5[e][4], q1.x, acc); acc = fmaf(w5[e][5], q1.y, acc);
        acc = fmaf(w5[e][6], q1.z, acc); acc = fmaf(w5[e][7], q1.w, acc);
      }
      last = acc;
      st[p^1][s][i] = acc;
    }
    __syncthreads();
    p ^= 1;
  }
  if (act) ws[c*WROW + sa*8 + i] = last;                  // [k][d*8+i]
  if (tid >= NOFF*8 && tid < WROW) ws[c*WROW + tid] = 0.0f;
  if (c == 0 && tid < 224) ws[FMOFF + tid] = fmats[tid];  // export fmats for edges
}

// ============ K2: edges (blocks 0,1) + interior conv (blocks 2..) ============
__global__ __launch_bounds__(CT) void kgm_conv_edges(
    const float* __restrict__ xs, const float* __restrict__ ys,
    const float* __restrict__ ws, float* __restrict__ out)
{
  __shared__ __align__(16) float shm[224 + 2*34*8];   // fm[224] + edge ping-pong
  const int tid = threadIdx.x;

  if (blockIdx.x >= 2) {
    // ---- conv path: R12's readlane conv, byte-identical math ----
    const int lane = tid & 63;
    const int ocol = STRIP + ((blockIdx.x - 2) * CT + tid) * CCPT;
    const int col0 = (ocol <= TLEN - STRIP - CCPT) ? ocol : (TLEN - STRIP - CCPT);

    float4 acc[8];
    #pragma unroll
    for (int i = 0; i < 8; ++i) acc[i] = make_float4(0.f, 0.f, 0.f, 0.f);

    #pragma unroll 2
    for (int k = 0; k < 12; ++k) {
      const float* src = ((k < 8) ? (xs + k*TLEN) : (ys + (k-8)*TLEN)) + col0;
      const float wA = ws[k*WROW + lane];
      const float wB = ws[k*WROW + 64 + lane];
      float z[20];
      #pragma unroll
      for (int j = 0; j < 5; ++j) {
        float4 v = *(const float4*)(src - 8 + 4*j);
        z[4*j] = v.x; z[4*j + 1] = v.y; z[4*j + 2] = v.z; z[4*j + 3] = v.w;
      }
      #pragma unroll
      for (int d = 0; d < NOFF; ++d) {
        #pragma unroll
        for (int i = 0; i < 8; ++i) {
          const int j = d*8 + i;                       // compile-time constant
          const int wi = __builtin_amdgcn_readlane(
              __float_as_int((j < 64) ? wA : wB), j & 63);
          const float w = __int_as_float(wi);
          acc[i].x = fmaf(w, z[d + 2], acc[i].x);
          acc[i].y = fmaf(w, z[d + 3], acc[i].y);
          acc[i].z = fmaf(w, z[d + 4], acc[i].z);
          acc[i].w = fmaf(w, z[d + 5], acc[i].w);
        }
      }
    }

    if (ocol < TLEN - STRIP) {   // 4-col groups all-or-nothing (499960 % 4 == 0)
      #pragma unroll
      for (int i = 0; i < 8; ++i)
        *(float4*)(out + i*TLEN + ocol) = acc[i];
    }
    return;
  }

  // ---- edge path (validated R12/R13 structure; fmats read from ws) ----
  float* const fm  = shm;                   // [224]
  float* const stf = shm + 224;             // ping-pong state, 2*34*8 (16B-aligned)
  const int BUF = 34*8;
  if (tid < 224) fm[tid] = ws[FMOFF + tid];
  for (int idx = tid; idx < 2*BUF; idx += 256) stf[idx] = 0.0f;
  __syncthreads();

  const int i = tid & 7;
  const int g = tid >> 3;                   // column within window
  float cmr[8], pmr[8], fur[7];
  #pragma unroll
  for (int k = 0; k < 8; ++k) {
    cmr[k] = fm[       k*8 + i];
    pmr[k] = fm[ 64 +  k*8 + i];
    if (k < 7) fur[k] = fm[128 + k*8 + i];
  }
  const bool left = (blockIdx.x == 0);
  const int col  = g;                       // 0..31
  const int gcol = left ? col : (TLEN - EWIN + col);
  const int sL = (col > 0) ? col - 1 : 0;
  const int sR = (col < EWIN - 1) ? col + 1 : EWIN - 1;
  const float xv = xs[i*TLEN + gcol];
  float gyv;
  {
    gyv = fm[192 +      i] * ys[0*TLEN + gcol];
    gyv = fmaf(fm[192 +  8 + i], ys[1*TLEN + gcol], gyv);
    gyv = fmaf(fm[192 + 16 + i], ys[2*TLEN + gcol], gyv);
    gyv = fmaf(fm[192 + 24 + i], ys[3*TLEN + gcol], gyv);
  }
  stf[col*8 + i] = xv;
  __syncthreads();
  int p = 0;
  float last = xv;
  #pragma unroll 1
  for (int it = 0; it < 2*NITER2; ++it) {
    const float* sp_ = stf + p*BUF;
    const float4 o0 = *(const float4*)(sp_ + col*8);
    const float4 o1 = *(const float4*)(sp_ + col*8 + 4);
    const float4 l0 = *(const float4*)(sp_ + sL*8);
    const float4 l1 = *(const float4*)(sp_ + sL*8 + 4);
    const float4 q0 = *(const float4*)(sp_ + sR*8);
    const float4 q1 = *(const float4*)(sp_ + sR*8 + 4);
    float a0 = gyv, a1 = 0.0f, a2 = 0.0f;
    a0 = fmaf(cmr[0], o0.x, a0); a0 = fmaf(cmr[1], o0.y, a0);
    a0 = fmaf(cmr[2], o0.z, a0); a0 = fmaf(cmr[3], o0.w, a0);
    a0 = fmaf(cmr[4], o1.x, a0); a0 = fmaf(cmr[5], o1.y, a0);
    a0 = fmaf(cmr[6], o1.z, a0); a0 = fmaf(cmr[7], o1.w, a0);
    a1 = fmaf(pmr[0], l0.x, a1); a1 = fmaf(pmr[1], l0.y, a1);
    a1 = fmaf(pmr[2], l0.z, a1); a1 = fmaf(pmr[3], l0.w, a1);
    a1 = fmaf(pmr[4], l1.x, a1); a1 = fmaf(pmr[5], l1.y, a1);
    a1 = fmaf(pmr[6], l1.z, a1); a1 = fmaf(pmr[7], l1.w, a1);
    a2 = fmaf(fur[0], q0.x, a2); a2 = fmaf(fur[1], q0.y, a2);
    a2 = fmaf(fur[2], q0.z, a2); a2 = fmaf(fur[3], q0.w, a2);
    a2 = fmaf(fur[4], q1.x, a2); a2 = fmaf(fur[5], q1.y, a2);
    a2 = fmaf(fur[6], q1.z, a2);
    last = a0 + a1 + a2;
    stf[(p^1)*BUF + col*8 + i] = last;
    __syncthreads();
    p ^= 1;
  }
  if (left ? (col < STRIP) : (col >= EWIN - STRIP)) out[i*TLEN + gcol] = last;
}

extern "C" void kernel_launch(void* const* d_in, const int* in_sizes, int n_in,
                              void* d_out, int out_size, void* d_ws, size_t ws_size,
                              hipStream_t stream)
{
  (void)in_sizes; (void)n_in; (void)out_size; (void)ws_size;
  const float* xs = (const float*)d_in[0];
  const float* ys = (const float*)d_in[1];
  const float* F  = (const float*)d_in[2];
  const float* H  = (const float*)d_in[3];
  const float* Q  = (const float*)d_in[4];
  const float* R  = (const float*)d_in[5];
  const float* ga = (const float*)d_in[6];
  float* ws  = (float*)d_ws;    // [0,1536): weights [k][d*8+i]; [1536,1760): fmats
  float* out = (float*)d_out;
  band_weights<<<12, 256, 0, stream>>>(F, H, Q, R, ga, ws);
  kgm_conv_edges<<<NCONV + 2, CT, 0, stream>>>(xs, ys, ws, out);
}